// Round 1
// baseline (629.120 us; speedup 1.0000x reference)
//
#include <hip/hip_runtime.h>
#include <hip/hip_bf16.h>
#include <stdint.h>

#define NF 8192
#define NX 2048
#define MROWS 8192
#define NGROUPS 32

typedef unsigned short u16;
typedef __bf16 bf16x8 __attribute__((ext_vector_type(8)));
typedef float f32x4 __attribute__((ext_vector_type(4)));

#define AS1 __attribute__((address_space(1)))
#define AS3 __attribute__((address_space(3)))

// async global->LDS, 16B per lane. LDS dest = wave-uniform base + lane*16,
// which matches per-lane &lds[t*8] when t = wave*64 + lane (guide §5, m97/m104).
__device__ __forceinline__ void glds16(const void* g, void* l) {
    __builtin_amdgcn_global_load_lds((AS1 void*)(uintptr_t)g,
                                     (AS3 void*)(uintptr_t)l, 16, 0, 0);
}

__device__ __forceinline__ u16 f2bf(float f) {
    unsigned u = __float_as_uint(f);
    return (u16)((u + 0x7FFFu + ((u >> 16) & 1u)) >> 16);  // RNE
}

// packed [NF, NX/2] (one byte per int32, two nibbles) -> W bf16 [NF, NX] row-major.
// W[f,2i] = (low - z)*s ; W[f,2i+1] = (high - z)*s ; group = (2i)/64.
__global__ void dequant_kernel(const int* __restrict__ packed,
                               const float* __restrict__ scales,
                               const int* __restrict__ zeros,
                               uint32_t* __restrict__ W2) {
    int tid = blockIdx.x * blockDim.x + threadIdx.x;   // [0, NF*NX/2)
    int f = tid >> 10;          // NX/2 = 1024 per row
    int i = tid & 1023;
    int g = f * NGROUPS + (i >> 5);
    int p = packed[tid];
    float s = scales[g];
    float z = (float)zeros[g];
    float w0 = ((float)(p & 15) - z) * s;
    float w1 = ((float)((p >> 4) & 15) - z) * s;
    W2[tid] = (uint32_t)f2bf(w0) | ((uint32_t)f2bf(w1) << 16);
}

// x fp32 -> bf16, 4 elems/thread
__global__ void cvt_kernel(const float4* __restrict__ x, ushort4* __restrict__ y) {
    int i = blockIdx.x * blockDim.x + threadIdx.x;
    float4 v = x[i];
    ushort4 o;
    o.x = f2bf(v.x); o.y = f2bf(v.y); o.z = f2bf(v.z); o.w = f2bf(v.w);
    y[i] = o;
}

// C[M,N] = A[M,K] * B[N,K]^T + bias ; 128x128 tile, BK=32, 4 waves (2x2 of 64x64),
// mfma_f32_16x16x32_bf16, global_load_lds width-16 staging (m97 structure).
__global__ __launch_bounds__(256)
void gemm_kernel(const u16* __restrict__ A, const u16* __restrict__ B,
                 const float* __restrict__ bias, float* __restrict__ C) {
    __shared__ __align__(16) u16 As[128 * 32];
    __shared__ __align__(16) u16 Bs[128 * 32];

    const int t = threadIdx.x;
    const int rowA0 = blockIdx.y * 128;
    const int rowB0 = blockIdx.x * 128;

    // staging: 512 chunks of 16B per tile; chunk c -> row c>>2, col offset (c&3)*8.
    // call0: c = t, call1: c = t + 256 (row + 64). LDS order matches chunk order.
    const u16* pa0 = A + (size_t)(rowA0 + (t >> 2)) * NX + (t & 3) * 8;
    const u16* pa1 = pa0 + (size_t)64 * NX;
    const u16* pb0 = B + (size_t)(rowB0 + (t >> 2)) * NX + (t & 3) * 8;
    const u16* pb1 = pb0 + (size_t)64 * NX;
    u16* sa0 = &As[t * 8];
    u16* sa1 = &As[(t + 256) * 8];
    u16* sb0 = &Bs[t * 8];
    u16* sb1 = &Bs[(t + 256) * 8];

    const int lane = t & 63;
    const int wv = t >> 6;
    const int wm = (wv & 1) * 64;   // wave row offset in tile
    const int wn = (wv >> 1) * 64;  // wave col offset in tile
    const int l15 = lane & 15;
    const int quad = lane >> 4;

    // A/B fragment source: row = (tileoff + l15), 8 contiguous k at quad*8 (16B aligned)
    const u16* Af = &As[(wm + l15) * 32 + quad * 8];
    const u16* Bf = &Bs[(wn + l15) * 32 + quad * 8];

    f32x4 acc[4][4];
#pragma unroll
    for (int i = 0; i < 4; ++i)
#pragma unroll
        for (int j = 0; j < 4; ++j) acc[i][j] = {0.f, 0.f, 0.f, 0.f};

    for (int kk = 0; kk < NX / 32; ++kk) {
        glds16(pa0, sa0);
        glds16(pa1, sa1);
        glds16(pb0, sb0);
        glds16(pb1, sb1);
        pa0 += 32; pa1 += 32; pb0 += 32; pb1 += 32;
        __syncthreads();  // drains vmcnt(0) then barrier: LDS tiles ready

        bf16x8 a[4], b[4];
#pragma unroll
        for (int i = 0; i < 4; ++i) a[i] = *(const bf16x8*)(Af + i * 16 * 32);
#pragma unroll
        for (int j = 0; j < 4; ++j) b[j] = *(const bf16x8*)(Bf + j * 16 * 32);
#pragma unroll
        for (int i = 0; i < 4; ++i)
#pragma unroll
            for (int j = 0; j < 4; ++j)
                acc[i][j] = __builtin_amdgcn_mfma_f32_16x16x32_bf16(a[i], b[j], acc[i][j], 0, 0, 0);

        __syncthreads();  // all waves done reading before next overwrite
    }

    // epilogue: C/D layout col = l15, row = quad*4 + reg (m89/m91 verified)
    const int col0 = rowB0 + wn + l15;
    const int row0 = rowA0 + wm + quad * 4;
    float bj[4];
#pragma unroll
    for (int j = 0; j < 4; ++j) bj[j] = bias[col0 + j * 16];
#pragma unroll
    for (int i = 0; i < 4; ++i) {
#pragma unroll
        for (int r = 0; r < 4; ++r) {
            float* crow = C + (size_t)(row0 + i * 16 + r) * NF;
#pragma unroll
            for (int j = 0; j < 4; ++j)
                crow[col0 + j * 16] = acc[i][j][r] + bj[j];
        }
    }
}

extern "C" void kernel_launch(void* const* d_in, const int* in_sizes, int n_in,
                              void* d_out, int out_size, void* d_ws, size_t ws_size,
                              hipStream_t stream) {
    const float* x      = (const float*)d_in[0];   // [4,2048,2048] fp32
    const int* packed   = (const int*)d_in[1];     // [8192,1024]
    const float* scales = (const float*)d_in[2];   // [8192,32]
    const int* zeros    = (const int*)d_in[3];     // [8192,32]
    const float* bias   = (const float*)d_in[4];   // [8192]
    float* out = (float*)d_out;                    // [8192, 8192] fp32

    // workspace: W bf16 (32 MiB) + x bf16 (32 MiB); fully rewritten every call
    u16* Wq = (u16*)d_ws;
    u16* Xb = Wq + (size_t)NF * NX;

    dequant_kernel<<<(NF * (NX / 2)) / 256, 256, 0, stream>>>(packed, scales, zeros, (uint32_t*)Wq);
    cvt_kernel<<<(MROWS * NX / 4) / 256, 256, 0, stream>>>((const float4*)x, (ushort4*)Xb);

    dim3 grid(NF / 128, MROWS / 128);
    gemm_kernel<<<grid, 256, 0, stream>>>(Xb, Wq, bias, out);
}